// Round 1
// baseline (385.972 us; speedup 1.0000x reference)
//
#include <hip/hip_runtime.h>

// Adaptive embedding: partition tokens by cluster, then gathered GEMM per cluster.
//
// Inputs (setup_inputs dict order):
//  d_in[0] input_ids int32 [16384]
//  d_in[1] emb0 f32 [20000,1024]   d_in[2] proj0 f32 [1024,1024]
//  d_in[3] emb1 f32 [20000,256]    d_in[4] proj1 f32 [1024,256]
//  d_in[5] emb2 f32 [160000,64]    d_in[6] proj2 f32 [1024,64]
//  d_in[7] emb3 f32 [67735,16]     d_in[8] proj3 f32 [1024,16]
// Output: f32 [8,2048,1024] = 16777216 elements.

constexpr int NTOK  = 16384;
constexpr int DPROJ = 1024;
constexpr float EMB_SCALE = 32.0f;   // sqrt(1024)

// ws layout: int cnt[4]; int lists[4][NTOK]  (262,160 bytes)

__global__ __launch_bounds__(256) void partition_kernel(
    const int* __restrict__ ids, int* __restrict__ cnt, int* __restrict__ lists)
{
    int t = blockIdx.x * 256 + threadIdx.x;
    if (t >= NTOK) return;
    int id = ids[t];
    int c = (id >= 200000) ? 3 : (id >= 40000) ? 2 : (id >= 20000) ? 1 : 0;
    int pos = atomicAdd(&cnt[c], 1);
    lists[c * NTOK + pos] = t;
}

// One 64(tokens) x 64(out-dims) tile. 256 threads, 4x4 micro-tile per thread.
// LDS tiles stored transposed [k][m] so the inner loop reads float4 (b128).
template<int D>
__device__ __forceinline__ void gemm_tile(
    const int* __restrict__ ids,
    const float* __restrict__ emb,
    const float* __restrict__ proj,
    const int* __restrict__ list,
    int count, int lo,
    float* __restrict__ out,
    float (*AsT)[68], float (*BsT)[68], int* smTok, int* smRow)
{
    const int m0 = blockIdx.x * 64;
    if (m0 >= count) return;
    const int n0 = blockIdx.y * 64;
    const int tid = threadIdx.x;

    if (tid < 64) {
        int m = m0 + tid;
        int tok = (m < count) ? list[m] : -1;
        smTok[tid] = tok;
        smRow[tid] = (tok >= 0) ? (ids[tok] - lo) : 0;
    }
    __syncthreads();

    const int lm = tid >> 2;          // 0..63 : tile row this thread loads
    const int lk = (tid & 3) << 2;    // 0,4,8,12 : k-offset (float4)
    const int tx = tid & 15;          // micro-tile col group
    const int ty = tid >> 4;          // micro-tile row group

    const float* arow = emb  + (size_t)smRow[lm] * D + lk;
    const float* brow = proj + (size_t)(n0 + lm) * D + lk;

    float acc[4][4] = {{0.f}};

    for (int k0 = 0; k0 < D; k0 += 16) {
        float4 av = *(const float4*)(arow + k0);
        float4 bv = *(const float4*)(brow + k0);
        __syncthreads();   // previous chunk's compute done before overwrite
        AsT[lk+0][lm] = av.x; AsT[lk+1][lm] = av.y;
        AsT[lk+2][lm] = av.z; AsT[lk+3][lm] = av.w;
        BsT[lk+0][lm] = bv.x; BsT[lk+1][lm] = bv.y;
        BsT[lk+2][lm] = bv.z; BsT[lk+3][lm] = bv.w;
        __syncthreads();
#pragma unroll
        for (int k = 0; k < 16; ++k) {
            float a[4], b[4];
            *(float4*)a = *(const float4*)&AsT[k][ty * 4];
            *(float4*)b = *(const float4*)&BsT[k][tx * 4];
#pragma unroll
            for (int i = 0; i < 4; ++i)
#pragma unroll
                for (int j = 0; j < 4; ++j)
                    acc[i][j] += a[i] * b[j];
        }
    }

#pragma unroll
    for (int i = 0; i < 4; ++i) {
        int tok = smTok[ty * 4 + i];
        if (tok < 0) continue;
        float4 v = make_float4(acc[i][0] * EMB_SCALE, acc[i][1] * EMB_SCALE,
                               acc[i][2] * EMB_SCALE, acc[i][3] * EMB_SCALE);
        *(float4*)(out + (size_t)tok * DPROJ + n0 + tx * 4) = v;
    }
}

__global__ __launch_bounds__(256) void adaptive_emb_gemm(
    const int* __restrict__ ids,
    const float* __restrict__ e0, const float* __restrict__ p0,
    const float* __restrict__ e1, const float* __restrict__ p1,
    const float* __restrict__ e2, const float* __restrict__ p2,
    const float* __restrict__ e3, const float* __restrict__ p3,
    const int* __restrict__ cnt, const int* __restrict__ lists,
    float* __restrict__ out)
{
    __shared__ float AsT[16][68];
    __shared__ float BsT[16][68];
    __shared__ int smTok[64];
    __shared__ int smRow[64];

    switch (blockIdx.z) {
    case 0: gemm_tile<1024>(ids, e0, p0, lists,            cnt[0], 0,      out, AsT, BsT, smTok, smRow); break;
    case 1: gemm_tile<256> (ids, e1, p1, lists + NTOK,     cnt[1], 20000,  out, AsT, BsT, smTok, smRow); break;
    case 2: gemm_tile<64>  (ids, e2, p2, lists + 2*NTOK,   cnt[2], 40000,  out, AsT, BsT, smTok, smRow); break;
    case 3: gemm_tile<16>  (ids, e3, p3, lists + 3*NTOK,   cnt[3], 200000, out, AsT, BsT, smTok, smRow); break;
    }
}

extern "C" void kernel_launch(void* const* d_in, const int* in_sizes, int n_in,
                              void* d_out, int out_size, void* d_ws, size_t ws_size,
                              hipStream_t stream) {
    const int*   ids = (const int*)d_in[0];
    const float* e0  = (const float*)d_in[1];
    const float* p0  = (const float*)d_in[2];
    const float* e1  = (const float*)d_in[3];
    const float* p1  = (const float*)d_in[4];
    const float* e2  = (const float*)d_in[5];
    const float* p2  = (const float*)d_in[6];
    const float* e3  = (const float*)d_in[7];
    const float* p3  = (const float*)d_in[8];
    float* out = (float*)d_out;

    int* cnt   = (int*)d_ws;
    int* lists = cnt + 4;

    hipMemsetAsync(cnt, 0, 4 * sizeof(int), stream);
    partition_kernel<<<dim3(NTOK / 256), 256, 0, stream>>>(ids, cnt, lists);

    // grid.x sized for worst case (all tokens in one cluster); empty tiles exit.
    dim3 grid(NTOK / 64, DPROJ / 64, 4);
    adaptive_emb_gemm<<<grid, 256, 0, stream>>>(
        ids, e0, p0, e1, p1, e2, p2, e3, p3, cnt, lists, out);
}

// Round 2
// 320.348 us; speedup vs baseline: 1.2049x; 1.2049x over previous
//
#include <hip/hip_runtime.h>

// Adaptive embedding: partition tokens by cluster (wave-aggregated atomics),
// then gathered GEMM per cluster: out[tok, :] = scale * emb_c[id] @ proj_c^T.
//
// Inputs: d_in[0] ids i32[16384]; (emb_i, proj_i) f32 pairs, d_i = 1024/256/64/16.
// Output: f32 [16384, 1024].

constexpr int NTOK  = 16384;
constexpr int DPROJ = 1024;
constexpr float EMB_SCALE = 32.0f;   // sqrt(1024)

// ws: int cnt[4]; int lists[4][NTOK]

__global__ __launch_bounds__(256) void partition_kernel(
    const int* __restrict__ ids, int* __restrict__ cnt, int* __restrict__ lists)
{
    int t = blockIdx.x * 256 + threadIdx.x;
    int id = ids[t];
    int c = (id >= 200000) ? 3 : (id >= 40000) ? 2 : (id >= 20000) ? 1 : 0;
    int lane = threadIdx.x & 63;
    unsigned long long lt = (1ull << lane) - 1ull;
    int pos = 0;
#pragma unroll
    for (int i = 0; i < 4; ++i) {
        unsigned long long m = __ballot(c == i);
        int b = 0;
        if (lane == 0 && m) b = atomicAdd(&cnt[i], (int)__popcll(m));
        b = __shfl(b, 0);
        if (c == i) pos = b + (int)__popcll(m & lt);
    }
    lists[c * NTOK + pos] = t;
}

// 64(tokens) x 128(out-dims) tile, BK k-chunk, 256 threads, 4x8 microtile.
// LDS transposed [k][m] (A pad 68, B pad 132) -> b128 reads, <=2-way banks.
template<int D, int BK>
__device__ __forceinline__ void gemm_tile(
    const int* __restrict__ ids,
    const float* __restrict__ emb,
    const float* __restrict__ proj,
    const int* __restrict__ list,
    int count, int lo,
    float* __restrict__ out,
    float (*AsT)[68], float (*BsT)[132], int* smTok, int* smRow)
{
    const int m0 = blockIdx.x * 64;
    if (m0 >= count) return;
    const int n0 = blockIdx.y * 128;
    const int tid = threadIdx.x;

    if (tid < 64) {
        int m = m0 + tid;
        int tok = (m < count) ? list[m] : -1;
        smTok[tid] = tok;
        smRow[tid] = (tok >= 0) ? (ids[tok] - lo) : 0;
    }
    __syncthreads();

    constexpr int K4 = BK / 4;                  // float4s per row per chunk
    constexpr int A4 = (64 * BK) / (256 * 4);   // A float4s per thread
    constexpr int B4 = (128 * BK) / (256 * 4);  // B float4s per thread

    const int tx = tid & 15;   // col group: cols tx*4 and 64+tx*4
    const int ty = tid >> 4;   // row group: rows ty*4..ty*4+3

    float acc[4][8] = {{0.f}};

    for (int k0 = 0; k0 < D; k0 += BK) {
        float4 areg[A4], breg[B4];
#pragma unroll
        for (int v = 0; v < A4; ++v) {
            int f = v * 256 + tid;
            int ar = f / K4, ak = f % K4;
            areg[v] = *(const float4*)(emb + (size_t)smRow[ar] * D + k0 + ak * 4);
        }
#pragma unroll
        for (int v = 0; v < B4; ++v) {
            int f = v * 256 + tid;
            int br = f / K4, bk = f % K4;
            breg[v] = *(const float4*)(proj + (size_t)(n0 + br) * D + k0 + bk * 4);
        }
        __syncthreads();
#pragma unroll
        for (int v = 0; v < A4; ++v) {
            int f = v * 256 + tid;
            int ar = f / K4, ak = (f % K4) * 4;
            AsT[ak+0][ar] = areg[v].x; AsT[ak+1][ar] = areg[v].y;
            AsT[ak+2][ar] = areg[v].z; AsT[ak+3][ar] = areg[v].w;
        }
#pragma unroll
        for (int v = 0; v < B4; ++v) {
            int f = v * 256 + tid;
            int br = f / K4, bk = (f % K4) * 4;
            BsT[bk+0][br] = breg[v].x; BsT[bk+1][br] = breg[v].y;
            BsT[bk+2][br] = breg[v].z; BsT[bk+3][br] = breg[v].w;
        }
        __syncthreads();
#pragma unroll
        for (int k = 0; k < BK; ++k) {
            float a[4], bl[4], bh[4];
            *(float4*)a  = *(const float4*)&AsT[k][ty * 4];
            *(float4*)bl = *(const float4*)&BsT[k][tx * 4];
            *(float4*)bh = *(const float4*)&BsT[k][64 + tx * 4];
#pragma unroll
            for (int i = 0; i < 4; ++i)
#pragma unroll
                for (int j = 0; j < 4; ++j) {
                    acc[i][j]     += a[i] * bl[j];
                    acc[i][j + 4] += a[i] * bh[j];
                }
        }
    }

#pragma unroll
    for (int i = 0; i < 4; ++i) {
        int tok = smTok[ty * 4 + i];
        if (tok < 0) continue;
        float* op = out + (size_t)tok * DPROJ + n0;
        float4 lo4 = make_float4(acc[i][0]*EMB_SCALE, acc[i][1]*EMB_SCALE,
                                 acc[i][2]*EMB_SCALE, acc[i][3]*EMB_SCALE);
        float4 hi4 = make_float4(acc[i][4]*EMB_SCALE, acc[i][5]*EMB_SCALE,
                                 acc[i][6]*EMB_SCALE, acc[i][7]*EMB_SCALE);
        *(float4*)(op + tx * 4)      = lo4;
        *(float4*)(op + 64 + tx * 4) = hi4;
    }
}

__global__ __launch_bounds__(256) void adaptive_emb_gemm(
    const int* __restrict__ ids,
    const float* __restrict__ e0, const float* __restrict__ p0,
    const float* __restrict__ e1, const float* __restrict__ p1,
    const float* __restrict__ e2, const float* __restrict__ p2,
    const float* __restrict__ e3, const float* __restrict__ p3,
    const int* __restrict__ cnt, const int* __restrict__ lists,
    float* __restrict__ out)
{
    __shared__ float AsT[32][68];
    __shared__ float BsT[32][132];
    __shared__ int smTok[64];
    __shared__ int smRow[64];

    switch (blockIdx.z) {
    case 0: gemm_tile<1024,32>(ids, e0, p0, lists,          cnt[0], 0,      out, AsT, BsT, smTok, smRow); break;
    case 1: gemm_tile<256, 32>(ids, e1, p1, lists + NTOK,   cnt[1], 20000,  out, AsT, BsT, smTok, smRow); break;
    case 2: gemm_tile<64,  32>(ids, e2, p2, lists + 2*NTOK, cnt[2], 40000,  out, AsT, BsT, smTok, smRow); break;
    case 3: gemm_tile<16,  16>(ids, e3, p3, lists + 3*NTOK, cnt[3], 200000, out, AsT, BsT, smTok, smRow); break;
    }
}

extern "C" void kernel_launch(void* const* d_in, const int* in_sizes, int n_in,
                              void* d_out, int out_size, void* d_ws, size_t ws_size,
                              hipStream_t stream) {
    const int*   ids = (const int*)d_in[0];
    const float* e0  = (const float*)d_in[1];
    const float* p0  = (const float*)d_in[2];
    const float* e1  = (const float*)d_in[3];
    const float* p1  = (const float*)d_in[4];
    const float* e2  = (const float*)d_in[5];
    const float* p2  = (const float*)d_in[6];
    const float* e3  = (const float*)d_in[7];
    const float* p3  = (const float*)d_in[8];
    float* out = (float*)d_out;

    int* cnt   = (int*)d_ws;
    int* lists = cnt + 4;

    hipMemsetAsync(cnt, 0, 4 * sizeof(int), stream);
    partition_kernel<<<dim3(NTOK / 256), 256, 0, stream>>>(ids, cnt, lists);

    dim3 grid(NTOK / 64, DPROJ / 128, 4);   // worst-case grid; empty tiles exit
    adaptive_emb_gemm<<<grid, 256, 0, stream>>>(
        ids, e0, p0, e1, p1, e2, p2, e3, p3, cnt, lists, out);
}

// Round 3
// 228.729 us; speedup vs baseline: 1.6875x; 1.4006x over previous
//
#include <hip/hip_runtime.h>

// Adaptive embedding: partition tokens by cluster (wave-aggregated atomics),
// then gathered bf16-MFMA GEMM per cluster:
//   out[tok,:] = 32 * emb_c[id] @ proj_c^T   (fp32 in, bf16 MFMA, fp32 out)
//
// d_in[0] ids i32[16384]; (emb_i f32[*,d_i], proj_i f32[1024,d_i]), d_i=1024/256/64/16
// out f32 [16384,1024]. ws: int cnt[4]; int lists[4][16384].

constexpr int NTOK  = 16384;
constexpr int DPROJ = 1024;
constexpr float EMB_SCALE = 32.0f;

typedef __attribute__((ext_vector_type(8))) short short8;   // 8 bf16 (4 VGPR)
typedef __attribute__((ext_vector_type(4))) float float4v;  // MFMA C/D

__global__ __launch_bounds__(256) void partition_kernel(
    const int* __restrict__ ids, int* __restrict__ cnt, int* __restrict__ lists)
{
    int t = blockIdx.x * 256 + threadIdx.x;
    int id = ids[t];
    int c = (id >= 200000) ? 3 : (id >= 40000) ? 2 : (id >= 20000) ? 1 : 0;
    int lane = threadIdx.x & 63;
    unsigned long long lt = (1ull << lane) - 1ull;
    int pos = 0;
#pragma unroll
    for (int i = 0; i < 4; ++i) {
        unsigned long long m = __ballot(c == i);
        int b = 0;
        if (lane == 0 && m) b = atomicAdd(&cnt[i], (int)__popcll(m));
        b = __shfl(b, 0);
        if (c == i) pos = b + (int)__popcll(m & lt);
    }
    lists[c * NTOK + pos] = t;
}

__device__ __forceinline__ short f2bf(float f) {  // RNE; inputs finite
    unsigned u = __builtin_bit_cast(unsigned, f);
    u += 0x7FFFu + ((u >> 16) & 1u);
    return (short)(u >> 16);
}

// 64(tokens) x 128(cols) tile, 4 waves; wave w owns cols [w*32, w*32+32).
// BK=32 chunk staged fp32->bf16 into LDS [rows][40] (pad 8 -> <=2-way banks).
template<int D>
__device__ __forceinline__ void gemm_tile(
    const int* __restrict__ ids,
    const float* __restrict__ emb,
    const float* __restrict__ proj,
    const int* __restrict__ list,
    int count, int lo,
    float* __restrict__ out,
    short (*Asm)[40], short (*Bsm)[40], int* smTok, int* smRow)
{
    const int m0 = blockIdx.y * 64;
    if (m0 >= count) return;
    const int n0 = blockIdx.x * 128;
    const int tid  = threadIdx.x;
    const int lane = tid & 63;
    const int wv   = tid >> 6;
    const int col  = lane & 15;
    const int quad = lane >> 4;

    if (tid < 64) {
        int m = m0 + tid;
        int tok = (m < count) ? list[m] : -1;
        smTok[tid] = tok;
        smRow[tid] = (tok >= 0) ? (ids[tok] - lo) : 0;
    }
    __syncthreads();

    const int ar = tid >> 2, ac = (tid & 3) * 8;    // A: 8 floats/thread
    const int br = tid >> 1, bc = (tid & 1) * 16;   // B: 16 floats/thread
    const float* arow = emb  + (size_t)smRow[ar] * D + ac;
    const float* brow = proj + (size_t)(n0 + br) * D + bc;

    float4v acc[4][2] = {};

    constexpr int CHUNKS = (D + 31) / 32;
    for (int kc = 0; kc < CHUNKS; ++kc) {
        const int k0 = kc * 32;
        float4 a0 = {}, a1 = {}, b0 = {}, b1 = {}, b2 = {}, b3 = {};
        if (ac + 0  < D || D >= 32) { /* fold for D>=32 */ }
        if (D >= 32 || ac + 0  < D) a0 = *(const float4*)(arow + k0);
        if (D >= 32 || ac + 4  < D) a1 = *(const float4*)(arow + k0 + 4);
        if (D >= 32 || bc + 0  < D) b0 = *(const float4*)(brow + k0);
        if (D >= 32 || bc + 4  < D) b1 = *(const float4*)(brow + k0 + 4);
        if (D >= 32 || bc + 8  < D) b2 = *(const float4*)(brow + k0 + 8);
        if (D >= 32 || bc + 12 < D) b3 = *(const float4*)(brow + k0 + 12);
        if (D == 16) {  // zero-pad cols >= 16
            if (ac >= 16) { a0 = float4{}; a1 = float4{}; }
            if (bc >= 16) { b0 = float4{}; b1 = float4{}; b2 = float4{}; b3 = float4{}; }
        }
        __syncthreads();   // previous chunk's frag reads done
        {
            short8 va = { f2bf(a0.x), f2bf(a0.y), f2bf(a0.z), f2bf(a0.w),
                          f2bf(a1.x), f2bf(a1.y), f2bf(a1.z), f2bf(a1.w) };
            *(short8*)&Asm[ar][ac] = va;
            short8 vb0 = { f2bf(b0.x), f2bf(b0.y), f2bf(b0.z), f2bf(b0.w),
                           f2bf(b1.x), f2bf(b1.y), f2bf(b1.z), f2bf(b1.w) };
            short8 vb1 = { f2bf(b2.x), f2bf(b2.y), f2bf(b2.z), f2bf(b2.w),
                           f2bf(b3.x), f2bf(b3.y), f2bf(b3.z), f2bf(b3.w) };
            *(short8*)&Bsm[br][bc]     = vb0;
            *(short8*)&Bsm[br][bc + 8] = vb1;
        }
        __syncthreads();

        short8 af[4], bf[2];
#pragma unroll
        for (int m = 0; m < 4; ++m)
            af[m] = *(const short8*)&Asm[m * 16 + col][quad * 8];
#pragma unroll
        for (int n = 0; n < 2; ++n)
            bf[n] = *(const short8*)&Bsm[wv * 32 + n * 16 + col][quad * 8];
#pragma unroll
        for (int m = 0; m < 4; ++m)
#pragma unroll
            for (int n = 0; n < 2; ++n)
                acc[m][n] = __builtin_amdgcn_mfma_f32_16x16x32_bf16(
                    af[m], bf[n], acc[m][n], 0, 0, 0);
    }

    // C/D layout: col = lane&15, row = quad*4 + reg
#pragma unroll
    for (int m = 0; m < 4; ++m) {
#pragma unroll
        for (int r = 0; r < 4; ++r) {
            int tok = smTok[m * 16 + quad * 4 + r];
            if (tok < 0) continue;
            float* op = out + (size_t)tok * DPROJ + n0 + wv * 32 + col;
            op[0]  = acc[m][0][r] * EMB_SCALE;
            op[16] = acc[m][1][r] * EMB_SCALE;
        }
    }
}

__global__ __launch_bounds__(256) void adaptive_emb_gemm(
    const int* __restrict__ ids,
    const float* __restrict__ e0, const float* __restrict__ p0,
    const float* __restrict__ e1, const float* __restrict__ p1,
    const float* __restrict__ e2, const float* __restrict__ p2,
    const float* __restrict__ e3, const float* __restrict__ p3,
    const int* __restrict__ cnt, const int* __restrict__ lists,
    float* __restrict__ out)
{
    __shared__ short Asm[64][40];
    __shared__ short Bsm[128][40];
    __shared__ int smTok[64];
    __shared__ int smRow[64];

    switch (blockIdx.z) {
    case 0: gemm_tile<1024>(ids, e0, p0, lists,          cnt[0], 0,      out, Asm, Bsm, smTok, smRow); break;
    case 1: gemm_tile<256> (ids, e1, p1, lists + NTOK,   cnt[1], 20000,  out, Asm, Bsm, smTok, smRow); break;
    case 2: gemm_tile<64>  (ids, e2, p2, lists + 2*NTOK, cnt[2], 40000,  out, Asm, Bsm, smTok, smRow); break;
    case 3: gemm_tile<16>  (ids, e3, p3, lists + 3*NTOK, cnt[3], 200000, out, Asm, Bsm, smTok, smRow); break;
    }
}

extern "C" void kernel_launch(void* const* d_in, const int* in_sizes, int n_in,
                              void* d_out, int out_size, void* d_ws, size_t ws_size,
                              hipStream_t stream) {
    const int*   ids = (const int*)d_in[0];
    const float* e0  = (const float*)d_in[1];
    const float* p0  = (const float*)d_in[2];
    const float* e1  = (const float*)d_in[3];
    const float* p1  = (const float*)d_in[4];
    const float* e2  = (const float*)d_in[5];
    const float* p2  = (const float*)d_in[6];
    const float* e3  = (const float*)d_in[7];
    const float* p3  = (const float*)d_in[8];
    float* out = (float*)d_out;

    int* cnt   = (int*)d_ws;
    int* lists = cnt + 4;

    hipMemsetAsync(cnt, 0, 4 * sizeof(int), stream);
    partition_kernel<<<dim3(NTOK / 256), 256, 0, stream>>>(ids, cnt, lists);

    // x = n-tile (8), y = m-tile (worst case 256), z = cluster.
    // Heavy cluster-0 blocks get consecutive linear ids -> spread across CUs.
    dim3 grid(DPROJ / 128, NTOK / 64, 4);
    adaptive_emb_gemm<<<grid, 256, 0, stream>>>(
        ids, e0, p0, e1, p1, e2, p2, e3, p3, cnt, lists, out);
}